// Round 2
// baseline (838.298 us; speedup 1.0000x reference)
//
#include <hip/hip_runtime.h>

// Problem constants (fixed by the reference).
#define N_AGENTS 32768
#define FEAT_DIM 64
#define N_FRAMES 64

// Native vector type so __builtin_nontemporal_{load,store} accepts it.
typedef float v4f __attribute__((ext_vector_type(4)));

// out[n, d, t] = mean over d' of in[n, d', t].
// One WAVE per agent. The agent tile in[n] is 64x64 fp32 = 16 KiB = 1024 float4.
// Viewed as 16 chunks of 1 KiB: chunk c, lane l -> float4 index c*64 + l,
// i.e. row d = 4c + (l>>4), cols t = (l&15)*4 .. +3.
// Every load/store instruction is one contiguous, aligned 1 KiB burst.
// Lane l accumulates rows d ≡ (l>>4) (mod 4); a 2-step shfl_xor(16,32)
// butterfly combines the 4 row-quad groups so every lane holds the full
// column sum for its 4 frames. Then 16 contiguous 1 KiB broadcast stores.
__global__ __launch_bounds__(256) void mean_bcast_wave(const v4f* __restrict__ in4,
                                                       v4f* __restrict__ out4) {
    const int gtid = blockIdx.x * blockDim.x + threadIdx.x;
    const int agent = gtid >> 6;          // one wave (64 lanes) per agent
    const int lane  = threadIdx.x & 63;
    const size_t base = (size_t)agent * (FEAT_DIM * N_FRAMES / 4) + lane;  // float4 units

    // Stream the whole 16 KiB tile with 16 independent 1 KiB loads (nt: no reuse).
    v4f v[16];
    #pragma unroll
    for (int c = 0; c < 16; ++c)
        v[c] = __builtin_nontemporal_load(&in4[base + c * 64]);

    v4f acc = v[0];
    #pragma unroll
    for (int c = 1; c < 16; ++c)
        acc += v[c];

    // Combine the 4 row-quad groups (lanes differing in bits 4 and 5).
    #pragma unroll
    for (int i = 0; i < 4; ++i) {
        float t = acc[i];
        t += __shfl_xor(t, 16);
        t += __shfl_xor(t, 32);
        acc[i] = t;
    }
    acc *= (1.0f / (float)FEAT_DIM);

    // Broadcast the per-column mean to all 64 rows: 16 contiguous 1 KiB stores.
    #pragma unroll
    for (int c = 0; c < 16; ++c)
        __builtin_nontemporal_store(acc, &out4[base + c * 64]);
}

extern "C" void kernel_launch(void* const* d_in, const int* in_sizes, int n_in,
                              void* d_out, int out_size, void* d_ws, size_t ws_size,
                              hipStream_t stream) {
    (void)in_sizes; (void)n_in; (void)d_ws; (void)ws_size; (void)out_size;
    // d_in[0]: in_features fp32 [32768, 64, 64]; d_in[1]: seq_start_end (unused — math is per-agent).
    const v4f* in4 = (const v4f*)d_in[0];
    v4f* out4      = (v4f*)d_out;

    const int total_threads = N_AGENTS * 64;   // one wave per agent
    const int block = 256;                     // 4 waves -> 4 consecutive agents per block
    const int grid  = total_threads / block;   // 8192
    mean_bcast_wave<<<grid, block, 0, stream>>>(in4, out4);
}